// Round 1
// baseline (602.041 us; speedup 1.0000x reference)
//
#include <hip/hip_runtime.h>

#define N_NODES 100000
#define N_EDGES 3200000
#define N_GRAPHS 2048

// ---------- CSR build ----------

__global__ void k_count_deg(const int* __restrict__ dst, int* __restrict__ cnt) {
  int e = blockIdx.x * blockDim.x + threadIdx.x;
  if (e < N_EDGES) atomicAdd(&cnt[dst[e]], 1);
}

__global__ void k_count_graph(const int* __restrict__ batch, int* __restrict__ gcnt) {
  int i = blockIdx.x * blockDim.x + threadIdx.x;
  if (i < N_NODES) atomicAdd(&gcnt[batch[i]], 1);
}

__global__ void k_dinv(const int* __restrict__ cnt, float* __restrict__ dinv) {
  int i = blockIdx.x * blockDim.x + threadIdx.x;
  if (i < N_NODES) dinv[i] = rsqrtf((float)(cnt[i] + 1));  // +1 self-loop; always > 0
}

// block-tile exclusive scan (tile = 256)
__global__ void k_scan1(const int* __restrict__ cnt, int* __restrict__ offs,
                        int* __restrict__ bsum) {
  __shared__ int sh[256];
  int tid = threadIdx.x;
  int i = blockIdx.x * 256 + tid;
  int v = (i < N_NODES) ? cnt[i] : 0;
  sh[tid] = v;
  __syncthreads();
  for (int off = 1; off < 256; off <<= 1) {
    int t = (tid >= off) ? sh[tid - off] : 0;
    __syncthreads();
    sh[tid] += t;
    __syncthreads();
  }
  if (i < N_NODES) offs[i] = sh[tid] - v;       // block-local exclusive
  if (tid == 255) bsum[blockIdx.x] = sh[255];   // tile total
}

__global__ void k_scan2(int* __restrict__ bsum, int nblocks) {
  __shared__ int sh[512];
  int tid = threadIdx.x;
  int v = (tid < nblocks) ? bsum[tid] : 0;
  sh[tid] = v;
  __syncthreads();
  for (int off = 1; off < 512; off <<= 1) {
    int t = (tid >= off) ? sh[tid - off] : 0;
    __syncthreads();
    sh[tid] += t;
    __syncthreads();
  }
  if (tid < nblocks) bsum[tid] = sh[tid] - v;   // exclusive over tile totals
}

__global__ void k_scan3(int* __restrict__ offs, const int* __restrict__ bsum) {
  int tid = threadIdx.x;
  int i = blockIdx.x * 256 + tid;
  if (i < N_NODES) offs[i] += bsum[blockIdx.x];
  if (i == 0) offs[N_NODES] = N_EDGES;          // total = E exactly
}

__global__ void k_fill(const int* __restrict__ src, const int* __restrict__ dst,
                       const int* __restrict__ offs, int* __restrict__ cur,
                       int* __restrict__ csr) {
  int e = blockIdx.x * blockDim.x + threadIdx.x;
  if (e < N_EDGES) {
    int d = dst[e];
    int p = atomicAdd(&cur[d], 1);
    csr[offs[d] + p] = src[e];
  }
}

// ---------- layer 1: h1 = x@W1; g1 = h1*dinv ----------

__global__ void k_t1(const float* __restrict__ x, const float* __restrict__ W1,
                     const float* __restrict__ dinv, float* __restrict__ g1) {
  __shared__ float w[150];
  int tid = threadIdx.x;
  if (tid < 150) w[tid] = W1[tid];
  __syncthreads();
  int gid = blockIdx.x * blockDim.x + tid;
  if (gid < N_NODES * 30) {
    int node = gid / 30, col = gid - node * 30;
    const float* xr = x + node * 5;
    float acc = 0.f;
#pragma unroll
    for (int k = 0; k < 5; k++) acc += xr[k] * w[k * 30 + col];
    g1[gid] = acc * dinv[node];
  }
}

// a1[d] = relu(dinv[d]*(g1[d] + sum_{s in N(d)} g1[s]) + b1)
// 32 lanes per node (30 active cols), 8 nodes per 256-block
__global__ void k_agg1(const float* __restrict__ g1, const float* __restrict__ dinv,
                       const int* __restrict__ offs, const int* __restrict__ csr,
                       const float* __restrict__ b1, float* __restrict__ a1) {
  int tid = threadIdx.x;
  int node = blockIdx.x * 8 + (tid >> 5);
  int col = tid & 31;
  if (node >= N_NODES) return;
  int beg = offs[node], end = offs[node + 1];
  float acc = (col < 30) ? g1[node * 30 + col] : 0.f;
  for (int k = beg; k < end; k++) {
    int s = csr[k];
    if (col < 30) acc += g1[s * 30 + col];
  }
  if (col < 30) {
    float v = dinv[node] * acc + b1[col];
    a1[node * 30 + col] = fmaxf(v, 0.f);
  }
}

// ---------- layer 2: h2 = a1@W2; g2 = h2*dinv ----------

__global__ void k_t2(const float* __restrict__ a1, const float* __restrict__ W2,
                     const float* __restrict__ dinv, float* __restrict__ g2) {
  __shared__ float w[240];
  int tid = threadIdx.x;
  if (tid < 240) w[tid] = W2[tid];
  __syncthreads();
  int gid = blockIdx.x * blockDim.x + tid;
  if (gid < N_NODES * 8) {
    int node = gid >> 3, col = gid & 7;
    const float* ar = a1 + node * 30;
    float acc = 0.f;
#pragma unroll
    for (int k = 0; k < 30; k++) acc += ar[k] * w[k * 8 + col];
    g2[gid] = acc * dinv[node];
  }
}

// out2[d] = dinv[d]*(g2[d] + sum g2[s]) + b2; pooled into gsum[batch[d]]
// 8 lanes per node, 32 nodes per 256-block
__global__ void k_agg2(const float* __restrict__ g2, const float* __restrict__ dinv,
                       const int* __restrict__ offs, const int* __restrict__ csr,
                       const float* __restrict__ b2, const int* __restrict__ batch,
                       float* __restrict__ gsum) {
  int tid = threadIdx.x;
  int node = blockIdx.x * 32 + (tid >> 3);
  int col = tid & 7;
  if (node >= N_NODES) return;
  int beg = offs[node], end = offs[node + 1];
  float acc = g2[node * 8 + col];
  for (int k = beg; k < end; k++) {
    int s = csr[k];
    acc += g2[s * 8 + col];
  }
  float v = dinv[node] * acc + b2[col];
  atomicAdd(&gsum[batch[node] * 8 + col], v);
}

__global__ void k_final(const float* __restrict__ gsum, const int* __restrict__ gcnt,
                        float* __restrict__ out) {
  int i = blockIdx.x * blockDim.x + threadIdx.x;
  if (i < N_GRAPHS * 8) {
    float c = (float)gcnt[i >> 3];
    out[i] = gsum[i] / fmaxf(c, 1.f);
  }
}

extern "C" void kernel_launch(void* const* d_in, const int* in_sizes, int n_in,
                              void* d_out, int out_size, void* d_ws, size_t ws_size,
                              hipStream_t stream) {
  const float* x    = (const float*)d_in[0];
  const int* ei     = (const int*)d_in[1];
  const int* batch  = (const int*)d_in[2];
  const float* W1   = (const float*)d_in[3];
  const float* b1   = (const float*)d_in[4];
  const float* W2   = (const float*)d_in[5];
  const float* b2   = (const float*)d_in[6];
  const int* srcp = ei;
  const int* dstp = ei + N_EDGES;
  float* out = (float*)d_out;

  // workspace carve (~39 MB total)
  char* base = (char*)d_ws;
  size_t o = 0;
  auto carve = [&](size_t bytes) -> char* {
    char* p = base + o;
    o += (bytes + 255) & ~(size_t)255;
    return p;
  };
  int* cnt    = (int*)carve((size_t)N_NODES * 4);        // deg count, later fill cursor
  int* offs   = (int*)carve((size_t)(N_NODES + 1) * 4);
  int* bsum   = (int*)carve(512 * 4);
  int* csr    = (int*)carve((size_t)N_EDGES * 4);
  float* dinv = (float*)carve((size_t)N_NODES * 4);
  float* g1   = (float*)carve((size_t)N_NODES * 30 * 4);
  float* a1   = (float*)carve((size_t)N_NODES * 30 * 4);
  float* gsum = (float*)carve((size_t)N_GRAPHS * 8 * 4);
  int* gcnt   = (int*)carve((size_t)N_GRAPHS * 4);
  float* g2   = g1;  // g1 dead after k_agg1; reuse for g2

  hipMemsetAsync(cnt, 0, (size_t)N_NODES * 4, stream);
  hipMemsetAsync(gsum, 0, (size_t)N_GRAPHS * 8 * 4, stream);
  hipMemsetAsync(gcnt, 0, (size_t)N_GRAPHS * 4, stream);

  int nb_e = (N_EDGES + 255) / 256;
  int nb_n = (N_NODES + 255) / 256;  // 391, also the scan tile count

  k_count_deg<<<nb_e, 256, 0, stream>>>(dstp, cnt);
  k_count_graph<<<nb_n, 256, 0, stream>>>(batch, gcnt);
  k_dinv<<<nb_n, 256, 0, stream>>>(cnt, dinv);
  k_scan1<<<nb_n, 256, 0, stream>>>(cnt, offs, bsum);
  k_scan2<<<1, 512, 0, stream>>>(bsum, nb_n);
  k_scan3<<<nb_n, 256, 0, stream>>>(offs, bsum);
  hipMemsetAsync(cnt, 0, (size_t)N_NODES * 4, stream);   // cursor reset
  k_fill<<<nb_e, 256, 0, stream>>>(srcp, dstp, offs, cnt, csr);

  k_t1<<<(N_NODES * 30 + 255) / 256, 256, 0, stream>>>(x, W1, dinv, g1);
  k_agg1<<<(N_NODES + 7) / 8, 256, 0, stream>>>(g1, dinv, offs, csr, b1, a1);
  k_t2<<<(N_NODES * 8 + 255) / 256, 256, 0, stream>>>(a1, W2, dinv, g2);
  k_agg2<<<(N_NODES + 31) / 32, 256, 0, stream>>>(g2, dinv, offs, csr, b2, batch, gsum);
  k_final<<<(N_GRAPHS * 8 + 255) / 256, 256, 0, stream>>>(gsum, gcnt, out);
}